// Round 19
// baseline (327.190 us; speedup 1.0000x reference)
//
#include <hip/hip_runtime.h>
#include <hip/hip_bf16.h>
#include <math.h>

#define IN_DIM 256
#define OUT_DIM 128
#define LEAKY 0.2f

typedef __attribute__((ext_vector_type(8))) short bf16x8;
typedef __attribute__((ext_vector_type(4))) float f32x4;
typedef __attribute__((ext_vector_type(16))) float f32x16;

__device__ __forceinline__ unsigned short f2bf(float f) {
    union { float f; unsigned int u; } v; v.f = f;
    unsigned int r = v.u + 0x7FFFu + ((v.u >> 16) & 1u);
    return (unsigned short)(r >> 16);
}
__device__ __forceinline__ float bf2f(unsigned int hi16) {
    union { unsigned int u; float f; } v; v.u = hi16 << 16;
    return v.f;
}

// ---------------- prep: blocks 0..15 = wswz (W_tgt -> bf16 fragment-major for
// 32x32x16: fragment f = kc*4+nc, lane l holds W[k=kc*16+(l>>5)*8+e][col=nc*32+(l&31)]),
// block 16 = wcomb = W_src @ a[0:128], blocks 17.. zero counts
__global__ __launch_bounds__(256) void prep_kernel(
    const float* __restrict__ W_src, const float* __restrict__ W_tgt,
    const float* __restrict__ a, float* __restrict__ wcomb,
    unsigned short* __restrict__ Wswz, int4* __restrict__ counts4, int n4) {
    if (blockIdx.x >= 17) {
        int i = (blockIdx.x - 17) * 256 + threadIdx.x;
        if (i < n4) counts4[i] = make_int4(0, 0, 0, 0);
        return;
    }
    if (blockIdx.x == 16) {
        int i = threadIdx.x;
        float s = 0.f;
        #pragma unroll 4
        for (int k = 0; k < OUT_DIM; ++k) s += W_src[i * OUT_DIM + k] * a[k];
        wcomb[i] = s;
        return;
    }
    int idx = blockIdx.x * 256 + threadIdx.x;   // 0..4095
    int l  = idx & 63;
    int f  = idx >> 6;         // 0..63 fragment
    int nc = f & 3;
    int kc = f >> 2;
    int col = nc * 32 + (l & 31);
    int kb  = kc * 16 + (l >> 5) * 8;
    unsigned int u[4];
    #pragma unroll
    for (int p = 0; p < 4; ++p) {
        unsigned short e0 = f2bf(W_tgt[(size_t)(kb + 2 * p + 0) * OUT_DIM + col]);
        unsigned short e1 = f2bf(W_tgt[(size_t)(kb + 2 * p + 1) * OUT_DIM + col]);
        u[p] = (unsigned int)e0 | ((unsigned int)e1 << 16);
    }
    *(uint4*)(Wswz + (size_t)idx * 8) = make_uint4(u[0], u[1], u[2], u[3]);
}

// ---------------- PHASE 1 (fused): gemm + gemv + hist, pattern of 8 blocks:
// r==0 -> gemm (1/8), r odd -> gemv (4/8), r in {2,4,6} -> hist (3/8).
// gemm: 32x32x16 MFMA, one wave = 32-row tile x 128 cols (4 ncol x 16 kc = 64
// MFMA per 32 rows -> half the MFMA instructions and half the B loads per row
// vs the 16x16 path). Zero LDS, zero barriers; A fragments loaded per-lane
// direct from global (R16-proven pattern, 32-wide shape).
__global__ __launch_bounds__(256) void phase1_kernel(
    const float* __restrict__ A, const unsigned short* __restrict__ Wswz,
    const float* __restrict__ a_hi, unsigned short* __restrict__ Hb,
    float* __restrict__ score_j, int Mt, int G,
    const float* __restrict__ X, const float* __restrict__ w,
    float* __restrict__ score_i, int Ms, int V,
    const int* __restrict__ src_id, int* __restrict__ counts,
    int* __restrict__ rank, int E, int H) {
    int b = blockIdx.x;
    int g = b >> 3;
    int r = b & 7;
    int tid = threadIdx.x;

    if (r != 0 && (r & 1) == 0) {
        // ---- hist branch (r = 2,4,6)
        int hb = g * 3 + ((r - 2) >> 1);
        if (hb >= H) return;
        int e = hb * 256 + tid;
        if (e < E) rank[e] = atomicAdd(&counts[src_id[e]], 1);
        return;
    }
    if (r & 1) {
        // ---- gemv branch (r = 1,3,5,7): 8 lanes/row, 8 x float4/lane, 32 rows/block
        int vb = g * 4 + ((r - 1) >> 1);
        if (vb >= V) return;
        int row = vb * 32 + (tid >> 3);
        if (row >= Ms) return;
        int k = tid & 7;
        const float4* R = (const float4*)(X + (size_t)row * IN_DIM);
        const float4* W4 = (const float4*)w;
        float s = 0.f;
        #pragma unroll
        for (int c = 0; c < 8; ++c) {
            float4 x = R[k + 8 * c];
            float4 wv = W4[k + 8 * c];
            s += x.x * wv.x + x.y * wv.y + x.z * wv.z + x.w * wv.w;
        }
        s += __shfl_xor(s, 1);
        s += __shfl_xor(s, 2);
        s += __shfl_xor(s, 4);
        if (k == 0) score_i[row] = s;
        return;
    }
    // ---- gemm branch (r == 0): wave-independent 32-row tiles
    if (g >= G) return;
    int w4 = tid >> 6;
    int l = tid & 63;
    int bm = g * 128 + w4 * 32;   // this wave's 32-row base
    int rl = l & 31;              // A row offset / B-C col lane
    int kh = l >> 5;              // k-subgroup 0/1

    int arow = bm + rl;
    const float* ap = A + (size_t)(arow < Mt ? arow : Mt - 1) * IN_DIM + kh * 8;
    const bf16x8* Wf = (const bf16x8*)Wswz;

    float aw[4];
    #pragma unroll
    for (int nc = 0; nc < 4; ++nc) aw[nc] = a_hi[nc * 32 + rl];

    f32x16 acc[4];
    #pragma unroll
    for (int nc = 0; nc < 4; ++nc)
        #pragma unroll
        for (int q = 0; q < 16; ++q) acc[nc][q] = 0.f;

    #pragma unroll
    for (int kc = 0; kc < 16; ++kc) {
        float4 a0 = *(const float4*)(ap + kc * 16);
        float4 a1 = *(const float4*)(ap + kc * 16 + 4);
        union { bf16x8 v; unsigned int u[4]; } fa;
        fa.u[0] = (unsigned int)f2bf(a0.x) | ((unsigned int)f2bf(a0.y) << 16);
        fa.u[1] = (unsigned int)f2bf(a0.z) | ((unsigned int)f2bf(a0.w) << 16);
        fa.u[2] = (unsigned int)f2bf(a1.x) | ((unsigned int)f2bf(a1.y) << 16);
        fa.u[3] = (unsigned int)f2bf(a1.z) | ((unsigned int)f2bf(a1.w) << 16);
        #pragma unroll
        for (int nc = 0; nc < 4; ++nc) {
            bf16x8 bfj = Wf[(size_t)(kc * 4 + nc) * 64 + l];
            acc[nc] = __builtin_amdgcn_mfma_f32_32x32x16_bf16(fa.v, bfj, acc[nc], 0, 0, 0);
        }
    }
    // epilogue: C/D layout col = l&31, row = (reg&3) + 8*(reg>>2) + 4*(l>>5)
    #pragma unroll
    for (int reg = 0; reg < 16; ++reg) {
        int row = bm + (reg & 3) + 8 * (reg >> 2) + 4 * kh;
        bool ok = row < Mt;
        float sj = 0.f;
        #pragma unroll
        for (int nc = 0; nc < 4; ++nc) {
            float v = acc[nc][reg];
            if (ok) Hb[(size_t)row * OUT_DIM + nc * 32 + rl] = f2bf(v);
            sj += v * aw[nc];
        }
        sj += __shfl_xor(sj, 1);
        sj += __shfl_xor(sj, 2);
        sj += __shfl_xor(sj, 4);
        sj += __shfl_xor(sj, 8);
        sj += __shfl_xor(sj, 16);
        if (rl == 0 && ok) score_j[row] = sj;
    }
}

// ---------------- 2-level exclusive scan (partial offs + block offsets)
__global__ __launch_bounds__(256) void scan1_kernel(
    const int* __restrict__ counts, int* __restrict__ offs,
    int* __restrict__ blockSums, int n) {
    __shared__ int sd[256];
    int b = blockIdx.x, tid = threadIdx.x;
    int base = b * 1024 + tid * 4;
    int v0 = base + 0 < n ? counts[base + 0] : 0;
    int v1 = base + 1 < n ? counts[base + 1] : 0;
    int v2 = base + 2 < n ? counts[base + 2] : 0;
    int v3 = base + 3 < n ? counts[base + 3] : 0;
    int p1 = v0, p2 = v0 + v1, p3 = v0 + v1 + v2;
    int tsum = p3 + v3;
    sd[tid] = tsum;
    __syncthreads();
    #pragma unroll
    for (int off = 1; off < 256; off <<= 1) {
        int t = tid >= off ? sd[tid - off] : 0;
        __syncthreads();
        sd[tid] += t;
        __syncthreads();
    }
    int ex = sd[tid] - tsum;
    if (base + 0 < n) offs[base + 0] = ex;
    if (base + 1 < n) offs[base + 1] = ex + p1;
    if (base + 2 < n) offs[base + 2] = ex + p2;
    if (base + 3 < n) offs[base + 3] = ex + p3;
    if (tid == 255) blockSums[b] = sd[255];
}

__global__ __launch_bounds__(256) void scan2_kernel(
    const int* __restrict__ blockSums, int* __restrict__ blockOffs, int nb) {
    __shared__ int sd[256];
    int tid = threadIdx.x;
    int v = tid < nb ? blockSums[tid] : 0;
    sd[tid] = v;
    __syncthreads();
    #pragma unroll
    for (int off = 1; off < 256; off <<= 1) {
        int t = tid >= off ? sd[tid - off] : 0;
        __syncthreads();
        sd[tid] += t;
        __syncthreads();
    }
    blockOffs[tid] = sd[tid] - v;
}

// ---------------- fused scatter, zero atomics; blockOffs folded in
__global__ __launch_bounds__(256) void scatter_fused_kernel(
    const int* __restrict__ src_id, const int* __restrict__ tgt_id,
    const float* __restrict__ score_i, const float* __restrict__ score_j,
    const int* __restrict__ offs, const int* __restrict__ blockOffs,
    const int* __restrict__ rank, uint2* __restrict__ pairs, int E) {
    int e = blockIdx.x * blockDim.x + threadIdx.x;
    if (e >= E) return;
    int s = src_id[e], t = tgt_id[e];
    float x = score_i[s] + score_j[t];
    x = x > 0.f ? x : LEAKY * x;
    x = fminf(30.f, fmaxf(-30.f, x));
    float ex = expf(x);
    int p = offs[s] + blockOffs[s >> 10] + rank[e];
    pairs[p] = make_uint2((unsigned int)t, __float_as_uint(ex));
}

// ---------------- aggregate: wave per node, 4 edges in flight, inline denom, fused ELU
__global__ __launch_bounds__(256) void agg_kernel(
    const uint2* __restrict__ pairs, const int* __restrict__ offs,
    const int* __restrict__ blockOffs, const unsigned short* __restrict__ hjb,
    float* __restrict__ out, int N, int E) {
    int node = (int)((blockIdx.x * (long long)blockDim.x + threadIdx.x) >> 6);
    if (node >= N) return;
    int lane = threadIdx.x & 63;
    int q  = lane >> 4;
    int cl = lane & 15;
    int beg = offs[node] + blockOffs[node >> 10];
    int end = (node + 1 < N) ? offs[node + 1] + blockOffs[(node + 1) >> 10] : E;
    int deg = end - beg;
    float den = 0.f;
    float acc[8];
    #pragma unroll
    for (int i = 0; i < 8; ++i) acc[i] = 0.f;

    int iters = (deg + 3) >> 2;
    for (int it = 0; it < iters; ++it) {
        int e = q + 4 * it;
        bool valid = e < deg;
        int idx = beg + (valid ? e : 0);
        uint2 tw = pairs[idx];
        int t = (int)tw.x;
        float wgt = valid ? __uint_as_float(tw.y) : 0.f;
        den += wgt;
        uint4 u = *(const uint4*)(hjb + (size_t)t * OUT_DIM + cl * 8);
        acc[0] += bf2f(u.x & 0xffffu) * wgt;
        acc[1] += bf2f(u.x >> 16) * wgt;
        acc[2] += bf2f(u.y & 0xffffu) * wgt;
        acc[3] += bf2f(u.y >> 16) * wgt;
        acc[4] += bf2f(u.z & 0xffffu) * wgt;
        acc[5] += bf2f(u.z >> 16) * wgt;
        acc[6] += bf2f(u.w & 0xffffu) * wgt;
        acc[7] += bf2f(u.w >> 16) * wgt;
    }
    den += __shfl_xor(den, 16);
    den += __shfl_xor(den, 32);
    float inv = 1.f / (den + 1e-8f);
    #pragma unroll
    for (int i = 0; i < 8; ++i) {
        acc[i] += __shfl_xor(acc[i], 16);
        acc[i] += __shfl_xor(acc[i], 32);
        acc[i] *= inv;
        acc[i] = acc[i] > 0.f ? acc[i] : expm1f(acc[i]);
    }
    if (lane < 16) {
        float4 v0 = make_float4(acc[0], acc[1], acc[2], acc[3]);
        float4 v1 = make_float4(acc[4], acc[5], acc[6], acc[7]);
        *(float4*)(out + (size_t)node * OUT_DIM + cl * 8) = v0;
        *(float4*)(out + (size_t)node * OUT_DIM + cl * 8 + 4) = v1;
    }
}

// ---------------- fallback path (atomic scatter) if ws too small
__global__ __launch_bounds__(256) void edge_pass1_kernel(
    const int* __restrict__ src_id, const int* __restrict__ tgt_id,
    const float* __restrict__ score_i, const float* __restrict__ score_j,
    float* __restrict__ exp_e, float* __restrict__ denom, int E) {
    int e = blockIdx.x * blockDim.x + threadIdx.x;
    if (e >= E) return;
    int s = src_id[e], t = tgt_id[e];
    float x = score_i[s] + score_j[t];
    x = x > 0.f ? x : LEAKY * x;
    x = fminf(30.f, fmaxf(-30.f, x));
    float ex = expf(x);
    exp_e[e] = ex;
    atomicAdd(&denom[s], ex);
}

__global__ __launch_bounds__(256) void edge_pass2_kernel(
    const int* __restrict__ src_id, const int* __restrict__ tgt_id,
    const unsigned short* __restrict__ hjb, const float* __restrict__ exp_e,
    const float* __restrict__ denom, float* __restrict__ out, int E) {
    int idx = blockIdx.x * blockDim.x + threadIdx.x;
    int e = idx >> 6;
    if (e >= E) return;
    int lane = idx & 63;
    int s = src_id[e], t = tgt_id[e];
    float alpha = exp_e[e] / (denom[s] + 1e-8f);
    unsigned int u = *(const unsigned int*)(hjb + (size_t)t * OUT_DIM + lane * 2);
    atomicAdd(out + (size_t)s * OUT_DIM + lane * 2 + 0, bf2f(u & 0xffffu) * alpha);
    atomicAdd(out + (size_t)s * OUT_DIM + lane * 2 + 1, bf2f(u >> 16) * alpha);
}

__global__ __launch_bounds__(256) void elu_kernel(float* __restrict__ out, int n4) {
    int i = blockIdx.x * blockDim.x + threadIdx.x;
    if (i >= n4) return;
    float4 v = ((float4*)out)[i];
    v.x = v.x > 0.f ? v.x : expm1f(v.x);
    v.y = v.y > 0.f ? v.y : expm1f(v.y);
    v.z = v.z > 0.f ? v.z : expm1f(v.z);
    v.w = v.w > 0.f ? v.w : expm1f(v.w);
    ((float4*)out)[i] = v;
}

extern "C" void kernel_launch(void* const* d_in, const int* in_sizes, int n_in,
                              void* d_out, int out_size, void* d_ws, size_t ws_size,
                              hipStream_t stream) {
    const float* src   = (const float*)d_in[0];
    const float* tgt   = (const float*)d_in[1];
    const float* W_src = (const float*)d_in[2];
    const float* W_tgt = (const float*)d_in[3];
    const float* a     = (const float*)d_in[4];
    const int*   edge  = (const int*)d_in[5];

    int N_src = in_sizes[0] / IN_DIM;
    int N_tgt = in_sizes[1] / IN_DIM;
    int E     = in_sizes[5] / 2;
    const int* src_id = edge;
    const int* tgt_id = edge + E;

    float* out = (float*)d_out;

    char* ws = (char*)d_ws;
    size_t off = 0;
    auto alloc = [&](size_t bytes) {
        void* p = ws + off;
        off += (bytes + 255) & ~(size_t)255;
        return p;
    };

    unsigned short* hjb  = (unsigned short*)alloc((size_t)N_tgt * OUT_DIM * 2);
    float* score_i = (float*)alloc((size_t)N_src * 4);
    float* score_j = (float*)alloc((size_t)N_tgt * 4);
    float* wcomb   = (float*)alloc(256 * 4);
    unsigned short* Wswz = (unsigned short*)alloc(4096 * 8 * 2);
    int*   counts    = (int*)alloc(((size_t)N_src + 3) / 4 * 16);  // int4-aligned
    int*   offs      = (int*)alloc((size_t)(N_src + 1) * 4);
    int*   blockSums = (int*)alloc(256 * 4);
    int*   blockOffs = (int*)alloc(256 * 4);
    float* denom     = (float*)alloc((size_t)N_src * 4);   // fallback only
    float* exp_e     = (float*)alloc((size_t)E * 4);       // fallback only
    size_t fb_need = off;
    int*   rank      = (int*)alloc((size_t)E * 4);
    uint2* pairs     = (uint2*)alloc((size_t)E * 8);
    size_t csr_need = off;
    (void)fb_need;

    bool use_csr = (ws_size >= csr_need);

    int n4 = (N_src + 3) / 4;                 // count of int4s to zero
    int zblocks = (n4 + 255) / 256;
    prep_kernel<<<17 + zblocks, 256, 0, stream>>>(
        W_src, W_tgt, a, wcomb, Wswz, (int4*)counts, n4);

    // fused phase 1: pattern of 8 = {1 gemm(128 rows), 4 gemv, 3 hist}
    int G = (N_tgt + 127) / 128;
    int V = (N_src + 31) / 32;
    int H = (E + 255) / 256;
    int vmax = (V + 3) / 4;
    int hmax = (H + 2) / 3;
    int groups = G > vmax ? G : vmax;
    if (hmax > groups) groups = hmax;
    phase1_kernel<<<groups * 8, 256, 0, stream>>>(
        tgt, Wswz, a + OUT_DIM, hjb, score_j, N_tgt, G,
        src, wcomb, score_i, N_src, V,
        src_id, counts, rank, E, H);

    if (use_csr) {
        int nb = (N_src + 1023) / 1024;
        scan1_kernel<<<nb, 256, 0, stream>>>(counts, offs, blockSums, N_src);
        scan2_kernel<<<1, 256, 0, stream>>>(blockSums, blockOffs, nb);
        scatter_fused_kernel<<<(E + 255) / 256, 256, 0, stream>>>(
            src_id, tgt_id, score_i, score_j, offs, blockOffs, rank, pairs, E);
        agg_kernel<<<(N_src + 3) / 4, 256, 0, stream>>>(
            pairs, offs, blockOffs, hjb, out, N_src, E);
    } else {
        hipMemsetAsync(out, 0, (size_t)N_src * OUT_DIM * sizeof(float), stream);
        hipMemsetAsync(denom, 0, (size_t)N_src * sizeof(float), stream);
        edge_pass1_kernel<<<(E + 255) / 256, 256, 0, stream>>>(
            src_id, tgt_id, score_i, score_j, exp_e, denom, E);
        edge_pass2_kernel<<<(int)(((long long)E * 64 + 255) / 256), 256, 0, stream>>>(
            src_id, tgt_id, hjb, exp_e, denom, out, E);
        elu_kernel<<<(N_src * OUT_DIM / 4 + 255) / 256, 256, 0, stream>>>(
            out, N_src * OUT_DIM / 4);
    }
}

// Round 20
// 144.748 us; speedup vs baseline: 2.2604x; 2.2604x over previous
//
#include <hip/hip_runtime.h>
#include <hip/hip_bf16.h>
#include <math.h>

#define IN_DIM 256
#define OUT_DIM 128
#define LEAKY 0.2f

typedef __attribute__((ext_vector_type(8))) short bf16x8;
typedef __attribute__((ext_vector_type(4))) float f32x4;

__device__ __forceinline__ unsigned short f2bf(float f) {
    union { float f; unsigned int u; } v; v.f = f;
    unsigned int r = v.u + 0x7FFFu + ((v.u >> 16) & 1u);
    return (unsigned short)(r >> 16);
}
__device__ __forceinline__ float bf2f(unsigned int hi16) {
    union { unsigned int u; float f; } v; v.u = hi16 << 16;
    return v.f;
}

// ---------------- prep: blocks 0..15 = wswz (W_tgt -> bf16 fragment-major),
//                  block 16 = wcomb = W_src @ a[0:128], blocks 17.. zero counts
__global__ __launch_bounds__(256) void prep_kernel(
    const float* __restrict__ W_src, const float* __restrict__ W_tgt,
    const float* __restrict__ a, float* __restrict__ wcomb,
    unsigned short* __restrict__ Wswz, int4* __restrict__ counts4, int n4) {
    if (blockIdx.x >= 17) {
        int i = (blockIdx.x - 17) * 256 + threadIdx.x;
        if (i < n4) counts4[i] = make_int4(0, 0, 0, 0);
        return;
    }
    if (blockIdx.x == 16) {
        int i = threadIdx.x;
        float s = 0.f;
        #pragma unroll 4
        for (int k = 0; k < OUT_DIM; ++k) s += W_src[i * OUT_DIM + k] * a[k];
        wcomb[i] = s;
        return;
    }
    int idx = blockIdx.x * 256 + threadIdx.x;   // 0..4095
    int l  = idx & 63;
    int fj = (idx >> 6) & 7;
    int kc = idx >> 9;
    int col = fj * 16 + (l & 15);
    int kb  = kc * 32 + (l >> 4) * 8;
    unsigned int u[4];
    #pragma unroll
    for (int p = 0; p < 4; ++p) {
        unsigned short e0 = f2bf(W_tgt[(size_t)(kb + 2 * p + 0) * OUT_DIM + col]);
        unsigned short e1 = f2bf(W_tgt[(size_t)(kb + 2 * p + 1) * OUT_DIM + col]);
        u[p] = (unsigned int)e0 | ((unsigned int)e1 << 16);
    }
    *(uint4*)(Wswz + (size_t)idx * 8) = make_uint4(u[0], u[1], u[2], u[3]);
}

// ---------------- PHASE 1 (fused): gemm + gemv + hist, interleaved block types.
// Pattern of 9: r in {0,4} gemm, r in {1,3,5,7} gemv, r in {2,6,8} hist.
// gemm = R13-proven 64-row/256-thr/32KB full-K staging; B register double
// buffer with sched_barrier(0) pinning the prefetch ABOVE the MFMA cluster
// (R17's Bbuf was sunk by the scheduler -> never materialized).
__global__ __launch_bounds__(256) void phase1_kernel(
    const float* __restrict__ A, const unsigned short* __restrict__ Wswz,
    const float* __restrict__ a_hi, unsigned short* __restrict__ Hb,
    float* __restrict__ score_j, int Mt, int G,
    const float* __restrict__ X, const float* __restrict__ w,
    float* __restrict__ score_i, int Ms, int V,
    const int* __restrict__ src_id, int* __restrict__ counts,
    int* __restrict__ rank, int E, int H) {
    __shared__ unsigned short As[64 * 256];  // 32 KB (gemm branch only)
    int b = blockIdx.x;
    int g = b / 9;
    int r = b - g * 9;
    int tid = threadIdx.x;

    if (r == 2 || r == 6 || r == 8) {
        // ---- hist branch
        int hb = g * 3 + (r == 6 ? 1 : (r == 8 ? 2 : 0));
        if (hb >= H) return;
        int e = hb * 256 + tid;
        if (e < E) rank[e] = atomicAdd(&counts[src_id[e]], 1);
        return;
    }
    if (r != 0 && r != 4) {
        // ---- gemv branch: 8 lanes/row, 8 x float4/lane, 32 rows/block
        int vb = g * 4 + (r == 3 ? 1 : (r == 5 ? 2 : (r == 7 ? 3 : 0)));
        if (vb >= V) return;
        int row = vb * 32 + (tid >> 3);
        if (row >= Ms) return;
        int k = tid & 7;
        const float4* R = (const float4*)(X + (size_t)row * IN_DIM);
        const float4* W4 = (const float4*)w;
        float s = 0.f;
        #pragma unroll
        for (int c = 0; c < 8; ++c) {
            float4 x = R[k + 8 * c];
            float4 wv = W4[k + 8 * c];
            s += x.x * wv.x + x.y * wv.y + x.z * wv.z + x.w * wv.w;
        }
        s += __shfl_xor(s, 1);
        s += __shfl_xor(s, 2);
        s += __shfl_xor(s, 4);
        if (k == 0) score_i[row] = s;
        return;
    }
    // ---- gemm branch (block-uniform; __syncthreads is safe)
    int gb = g * 2 + (r == 4 ? 1 : 0);
    if (gb >= G) return;
    int w4 = tid >> 6;
    int l = tid & 63;
    int bm = gb * 64;

    int srow = tid >> 4;          // 0..15
    int kcol = (tid & 15) * 4;    // 0..60

    float aw[8];
    #pragma unroll
    for (int j = 0; j < 8; ++j) aw[j] = a_hi[j * 16 + (l & 15)];

    f32x4 acc[8];
    f32x4 zero = {0.f, 0.f, 0.f, 0.f};
    #pragma unroll
    for (int j = 0; j < 8; ++j) acc[j] = zero;

    float4 pre[16];
    #pragma unroll
    for (int p = 0; p < 4; ++p) {
        int grow = bm + srow + p * 16;
        const float* rp = A + (size_t)(grow < Mt ? grow : Mt - 1) * IN_DIM;
        bool ok = grow < Mt;
        #pragma unroll
        for (int c = 0; c < 4; ++c) {
            float4 v = *(const float4*)(rp + c * 64 + kcol);
            pre[p * 4 + c] = ok ? v : make_float4(0.f, 0.f, 0.f, 0.f);
        }
    }
    #pragma unroll
    for (int p = 0; p < 4; ++p) {
        int row = srow + p * 16;
        #pragma unroll
        for (int c = 0; c < 4; ++c) {
            float4 v = pre[p * 4 + c];
            unsigned int b0 = (unsigned int)f2bf(v.x) | ((unsigned int)f2bf(v.y) << 16);
            unsigned int b1 = (unsigned int)f2bf(v.z) | ((unsigned int)f2bf(v.w) << 16);
            unsigned int byteoff =
                (unsigned int)(row * 512 + (c * 64 + kcol) * 2) ^ ((row & 7) << 4);
            *(uint2*)((char*)As + byteoff) = make_uint2(b0, b1);
        }
    }
    __syncthreads();

    // MFMA loop, B double-buffered in registers. sched_barrier(0) after the
    // prefetch block prevents the scheduler from sinking the loads below the
    // MFMAs (R17 failure mode). kc fully unrolled -> static Bbuf indices.
    const bf16x8* Wf = (const bf16x8*)Wswz;
    int arow = w4 * 16 + (l & 15);
    bf16x8 Bbuf[2][8];
    #pragma unroll
    for (int j = 0; j < 8; ++j) Bbuf[0][j] = Wf[(size_t)j * 64 + l];
    #pragma unroll
    for (int kc = 0; kc < 8; ++kc) {
        const int cur = kc & 1, nxt = cur ^ 1;
        if (kc < 7) {
            #pragma unroll
            for (int j = 0; j < 8; ++j)
                Bbuf[nxt][j] = Wf[(size_t)((kc + 1) * 8 + j) * 64 + l];
            __builtin_amdgcn_sched_barrier(0);   // pin prefetch above MFMAs
        }
        unsigned int byteoff =
            (unsigned int)(arow * 512 + kc * 64 + (l >> 4) * 16) ^ ((arow & 7) << 4);
        bf16x8 af = *(const bf16x8*)((const char*)As + byteoff);
        #pragma unroll
        for (int j = 0; j < 8; ++j)
            acc[j] = __builtin_amdgcn_mfma_f32_16x16x32_bf16(af, Bbuf[cur][j], acc[j], 0, 0, 0);
    }
    #pragma unroll
    for (int rr = 0; rr < 4; ++rr) {
        int row = bm + w4 * 16 + (l >> 4) * 4 + rr;
        if (row < Mt) {
            float s = 0.f;
            #pragma unroll
            for (int j = 0; j < 8; ++j) {
                float v = acc[j][rr];
                Hb[(size_t)row * OUT_DIM + j * 16 + (l & 15)] = f2bf(v);
                s += v * aw[j];
            }
            s += __shfl_xor(s, 1); s += __shfl_xor(s, 2);
            s += __shfl_xor(s, 4); s += __shfl_xor(s, 8);
            if ((l & 15) == 0) score_j[row] = s;
        }
    }
}

// ---------------- 2-level exclusive scan (partial offs + block offsets)
__global__ __launch_bounds__(256) void scan1_kernel(
    const int* __restrict__ counts, int* __restrict__ offs,
    int* __restrict__ blockSums, int n) {
    __shared__ int sd[256];
    int b = blockIdx.x, tid = threadIdx.x;
    int base = b * 1024 + tid * 4;
    int v0 = base + 0 < n ? counts[base + 0] : 0;
    int v1 = base + 1 < n ? counts[base + 1] : 0;
    int v2 = base + 2 < n ? counts[base + 2] : 0;
    int v3 = base + 3 < n ? counts[base + 3] : 0;
    int p1 = v0, p2 = v0 + v1, p3 = v0 + v1 + v2;
    int tsum = p3 + v3;
    sd[tid] = tsum;
    __syncthreads();
    #pragma unroll
    for (int off = 1; off < 256; off <<= 1) {
        int t = tid >= off ? sd[tid - off] : 0;
        __syncthreads();
        sd[tid] += t;
        __syncthreads();
    }
    int ex = sd[tid] - tsum;
    if (base + 0 < n) offs[base + 0] = ex;
    if (base + 1 < n) offs[base + 1] = ex + p1;
    if (base + 2 < n) offs[base + 2] = ex + p2;
    if (base + 3 < n) offs[base + 3] = ex + p3;
    if (tid == 255) blockSums[b] = sd[255];
}

__global__ __launch_bounds__(256) void scan2_kernel(
    const int* __restrict__ blockSums, int* __restrict__ blockOffs, int nb) {
    __shared__ int sd[256];
    int tid = threadIdx.x;
    int v = tid < nb ? blockSums[tid] : 0;
    sd[tid] = v;
    __syncthreads();
    #pragma unroll
    for (int off = 1; off < 256; off <<= 1) {
        int t = tid >= off ? sd[tid - off] : 0;
        __syncthreads();
        sd[tid] += t;
        __syncthreads();
    }
    blockOffs[tid] = sd[tid] - v;
}

// ---------------- fused scatter, zero atomics; blockOffs folded in
__global__ __launch_bounds__(256) void scatter_fused_kernel(
    const int* __restrict__ src_id, const int* __restrict__ tgt_id,
    const float* __restrict__ score_i, const float* __restrict__ score_j,
    const int* __restrict__ offs, const int* __restrict__ blockOffs,
    const int* __restrict__ rank, uint2* __restrict__ pairs, int E) {
    int e = blockIdx.x * blockDim.x + threadIdx.x;
    if (e >= E) return;
    int s = src_id[e], t = tgt_id[e];
    float x = score_i[s] + score_j[t];
    x = x > 0.f ? x : LEAKY * x;
    x = fminf(30.f, fmaxf(-30.f, x));
    float ex = expf(x);
    int p = offs[s] + blockOffs[s >> 10] + rank[e];
    pairs[p] = make_uint2((unsigned int)t, __float_as_uint(ex));
}

// ---------------- aggregate: wave per node, 4 edges in flight, inline denom, fused ELU
__global__ __launch_bounds__(256) void agg_kernel(
    const uint2* __restrict__ pairs, const int* __restrict__ offs,
    const int* __restrict__ blockOffs, const unsigned short* __restrict__ hjb,
    float* __restrict__ out, int N, int E) {
    int node = (int)((blockIdx.x * (long long)blockDim.x + threadIdx.x) >> 6);
    if (node >= N) return;
    int lane = threadIdx.x & 63;
    int q  = lane >> 4;
    int cl = lane & 15;
    int beg = offs[node] + blockOffs[node >> 10];
    int end = (node + 1 < N) ? offs[node + 1] + blockOffs[(node + 1) >> 10] : E;
    int deg = end - beg;
    float den = 0.f;
    float acc[8];
    #pragma unroll
    for (int i = 0; i < 8; ++i) acc[i] = 0.f;

    int iters = (deg + 3) >> 2;
    for (int it = 0; it < iters; ++it) {
        int e = q + 4 * it;
        bool valid = e < deg;
        int idx = beg + (valid ? e : 0);
        uint2 tw = pairs[idx];
        int t = (int)tw.x;
        float wgt = valid ? __uint_as_float(tw.y) : 0.f;
        den += wgt;
        uint4 u = *(const uint4*)(hjb + (size_t)t * OUT_DIM + cl * 8);
        acc[0] += bf2f(u.x & 0xffffu) * wgt;
        acc[1] += bf2f(u.x >> 16) * wgt;
        acc[2] += bf2f(u.y & 0xffffu) * wgt;
        acc[3] += bf2f(u.y >> 16) * wgt;
        acc[4] += bf2f(u.z & 0xffffu) * wgt;
        acc[5] += bf2f(u.z >> 16) * wgt;
        acc[6] += bf2f(u.w & 0xffffu) * wgt;
        acc[7] += bf2f(u.w >> 16) * wgt;
    }
    den += __shfl_xor(den, 16);
    den += __shfl_xor(den, 32);
    float inv = 1.f / (den + 1e-8f);
    #pragma unroll
    for (int i = 0; i < 8; ++i) {
        acc[i] += __shfl_xor(acc[i], 16);
        acc[i] += __shfl_xor(acc[i], 32);
        acc[i] *= inv;
        acc[i] = acc[i] > 0.f ? acc[i] : expm1f(acc[i]);
    }
    if (lane < 16) {
        float4 v0 = make_float4(acc[0], acc[1], acc[2], acc[3]);
        float4 v1 = make_float4(acc[4], acc[5], acc[6], acc[7]);
        *(float4*)(out + (size_t)node * OUT_DIM + cl * 8) = v0;
        *(float4*)(out + (size_t)node * OUT_DIM + cl * 8 + 4) = v1;
    }
}

// ---------------- fallback path (atomic scatter) if ws too small
__global__ __launch_bounds__(256) void edge_pass1_kernel(
    const int* __restrict__ src_id, const int* __restrict__ tgt_id,
    const float* __restrict__ score_i, const float* __restrict__ score_j,
    float* __restrict__ exp_e, float* __restrict__ denom, int E) {
    int e = blockIdx.x * blockDim.x + threadIdx.x;
    if (e >= E) return;
    int s = src_id[e], t = tgt_id[e];
    float x = score_i[s] + score_j[t];
    x = x > 0.f ? x : LEAKY * x;
    x = fminf(30.f, fmaxf(-30.f, x));
    float ex = expf(x);
    exp_e[e] = ex;
    atomicAdd(&denom[s], ex);
}

__global__ __launch_bounds__(256) void edge_pass2_kernel(
    const int* __restrict__ src_id, const int* __restrict__ tgt_id,
    const unsigned short* __restrict__ hjb, const float* __restrict__ exp_e,
    const float* __restrict__ denom, float* __restrict__ out, int E) {
    int idx = blockIdx.x * blockDim.x + threadIdx.x;
    int e = idx >> 6;
    if (e >= E) return;
    int lane = idx & 63;
    int s = src_id[e], t = tgt_id[e];
    float alpha = exp_e[e] / (denom[s] + 1e-8f);
    unsigned int u = *(const unsigned int*)(hjb + (size_t)t * OUT_DIM + lane * 2);
    atomicAdd(out + (size_t)s * OUT_DIM + lane * 2 + 0, bf2f(u & 0xffffu) * alpha);
    atomicAdd(out + (size_t)s * OUT_DIM + lane * 2 + 1, bf2f(u >> 16) * alpha);
}

__global__ __launch_bounds__(256) void elu_kernel(float* __restrict__ out, int n4) {
    int i = blockIdx.x * blockDim.x + threadIdx.x;
    if (i >= n4) return;
    float4 v = ((float4*)out)[i];
    v.x = v.x > 0.f ? v.x : expm1f(v.x);
    v.y = v.y > 0.f ? v.y : expm1f(v.y);
    v.z = v.z > 0.f ? v.z : expm1f(v.z);
    v.w = v.w > 0.f ? v.w : expm1f(v.w);
    ((float4*)out)[i] = v;
}

extern "C" void kernel_launch(void* const* d_in, const int* in_sizes, int n_in,
                              void* d_out, int out_size, void* d_ws, size_t ws_size,
                              hipStream_t stream) {
    const float* src   = (const float*)d_in[0];
    const float* tgt   = (const float*)d_in[1];
    const float* W_src = (const float*)d_in[2];
    const float* W_tgt = (const float*)d_in[3];
    const float* a     = (const float*)d_in[4];
    const int*   edge  = (const int*)d_in[5];

    int N_src = in_sizes[0] / IN_DIM;
    int N_tgt = in_sizes[1] / IN_DIM;
    int E     = in_sizes[5] / 2;
    const int* src_id = edge;
    const int* tgt_id = edge + E;

    float* out = (float*)d_out;

    char* ws = (char*)d_ws;
    size_t off = 0;
    auto alloc = [&](size_t bytes) {
        void* p = ws + off;
        off += (bytes + 255) & ~(size_t)255;
        return p;
    };

    unsigned short* hjb  = (unsigned short*)alloc((size_t)N_tgt * OUT_DIM * 2);
    float* score_i = (float*)alloc((size_t)N_src * 4);
    float* score_j = (float*)alloc((size_t)N_tgt * 4);
    float* wcomb   = (float*)alloc(256 * 4);
    unsigned short* Wswz = (unsigned short*)alloc(4096 * 8 * 2);
    int*   counts    = (int*)alloc(((size_t)N_src + 3) / 4 * 16);  // int4-aligned
    int*   offs      = (int*)alloc((size_t)(N_src + 1) * 4);
    int*   blockSums = (int*)alloc(256 * 4);
    int*   blockOffs = (int*)alloc(256 * 4);
    float* denom     = (float*)alloc((size_t)N_src * 4);   // fallback only
    float* exp_e     = (float*)alloc((size_t)E * 4);       // fallback only
    size_t fb_need = off;
    int*   rank      = (int*)alloc((size_t)E * 4);
    uint2* pairs     = (uint2*)alloc((size_t)E * 8);
    size_t csr_need = off;
    (void)fb_need;

    bool use_csr = (ws_size >= csr_need);

    int n4 = (N_src + 3) / 4;                 // count of int4s to zero
    int zblocks = (n4 + 255) / 256;
    prep_kernel<<<17 + zblocks, 256, 0, stream>>>(
        W_src, W_tgt, a, wcomb, Wswz, (int4*)counts, n4);

    // fused phase 1: gemm + gemv + hist (pattern of 9: 2 gemm, 4 gemv, 3 hist)
    int G = (N_tgt + 63) / 64;
    int V = (N_src + 31) / 32;
    int H = (E + 255) / 256;
    int gmax = (G + 1) / 2;
    int vmax = (V + 3) / 4;
    int hmax = (H + 2) / 3;
    int groups = gmax > vmax ? gmax : vmax;
    if (hmax > groups) groups = hmax;
    phase1_kernel<<<groups * 9, 256, 0, stream>>>(
        tgt, Wswz, a + OUT_DIM, hjb, score_j, N_tgt, G,
        src, wcomb, score_i, N_src, V,
        src_id, counts, rank, E, H);

    if (use_csr) {
        int nb = (N_src + 1023) / 1024;
        scan1_kernel<<<nb, 256, 0, stream>>>(counts, offs, blockSums, N_src);
        scan2_kernel<<<1, 256, 0, stream>>>(blockSums, blockOffs, nb);
        scatter_fused_kernel<<<(E + 255) / 256, 256, 0, stream>>>(
            src_id, tgt_id, score_i, score_j, offs, blockOffs, rank, pairs, E);
        agg_kernel<<<(N_src + 3) / 4, 256, 0, stream>>>(
            pairs, offs, blockOffs, hjb, out, N_src, E);
    } else {
        hipMemsetAsync(out, 0, (size_t)N_src * OUT_DIM * sizeof(float), stream);
        hipMemsetAsync(denom, 0, (size_t)N_src * sizeof(float), stream);
        edge_pass1_kernel<<<(E + 255) / 256, 256, 0, stream>>>(
            src_id, tgt_id, score_i, score_j, exp_e, denom, E);
        edge_pass2_kernel<<<(int)(((long long)E * 64 + 255) / 256), 256, 0, stream>>>(
            src_id, tgt_id, hjb, exp_e, denom, out, E);
        elu_kernel<<<(N_src * OUT_DIM / 4 + 255) / 256, 256, 0, stream>>>(
            out, N_src * OUT_DIM / 4);
    }
}

// Round 21
// 142.288 us; speedup vs baseline: 2.2995x; 1.0173x over previous
//
#include <hip/hip_runtime.h>
#include <hip/hip_bf16.h>
#include <math.h>

#define IN_DIM 256
#define OUT_DIM 128
#define LEAKY 0.2f

typedef __attribute__((ext_vector_type(8))) short bf16x8;
typedef __attribute__((ext_vector_type(4))) float f32x4;

__device__ __forceinline__ unsigned short f2bf(float f) {
    union { float f; unsigned int u; } v; v.f = f;
    unsigned int r = v.u + 0x7FFFu + ((v.u >> 16) & 1u);
    return (unsigned short)(r >> 16);
}
__device__ __forceinline__ float bf2f(unsigned int hi16) {
    union { unsigned int u; float f; } v; v.u = hi16 << 16;
    return v.f;
}

// ---------------- prep: blocks 0..15 = wswz (W_tgt -> bf16 fragment-major),
//                  block 16 = wcomb = W_src @ a[0:128], blocks 17.. zero counts
__global__ __launch_bounds__(256) void prep_kernel(
    const float* __restrict__ W_src, const float* __restrict__ W_tgt,
    const float* __restrict__ a, float* __restrict__ wcomb,
    unsigned short* __restrict__ Wswz, int4* __restrict__ counts4, int n4) {
    if (blockIdx.x >= 17) {
        int i = (blockIdx.x - 17) * 256 + threadIdx.x;
        if (i < n4) counts4[i] = make_int4(0, 0, 0, 0);
        return;
    }
    if (blockIdx.x == 16) {
        int i = threadIdx.x;
        float s = 0.f;
        #pragma unroll 4
        for (int k = 0; k < OUT_DIM; ++k) s += W_src[i * OUT_DIM + k] * a[k];
        wcomb[i] = s;
        return;
    }
    int idx = blockIdx.x * 256 + threadIdx.x;   // 0..4095
    int l  = idx & 63;
    int fj = (idx >> 6) & 7;
    int kc = idx >> 9;
    int col = fj * 16 + (l & 15);
    int kb  = kc * 32 + (l >> 4) * 8;
    unsigned int u[4];
    #pragma unroll
    for (int p = 0; p < 4; ++p) {
        unsigned short e0 = f2bf(W_tgt[(size_t)(kb + 2 * p + 0) * OUT_DIM + col]);
        unsigned short e1 = f2bf(W_tgt[(size_t)(kb + 2 * p + 1) * OUT_DIM + col]);
        u[p] = (unsigned int)e0 | ((unsigned int)e1 << 16);
    }
    *(uint4*)(Wswz + (size_t)idx * 8) = make_uint4(u[0], u[1], u[2], u[3]);
}

// ---------------- PHASE 1 (fused): gemm + gemv + hist, interleaved block types.
// Pattern of 9: r in {0,4} gemm, r in {1,3,5,7} gemv, r in {2,6,8} hist.
// gemm = R13-proven 64-row/256-thr/32KB full-K staging. setprio(1) wraps the
// MFMA cluster (T5): pays ONLY with wave role-diversity on the CU, which this
// fused grid has (gemv/hist memory-waves co-resident with gemm MFMA-waves).
__global__ __launch_bounds__(256) void phase1_kernel(
    const float* __restrict__ A, const unsigned short* __restrict__ Wswz,
    const float* __restrict__ a_hi, unsigned short* __restrict__ Hb,
    float* __restrict__ score_j, int Mt, int G,
    const float* __restrict__ X, const float* __restrict__ w,
    float* __restrict__ score_i, int Ms, int V,
    const int* __restrict__ src_id, int* __restrict__ counts,
    int* __restrict__ rank, int E, int H) {
    __shared__ unsigned short As[64 * 256];  // 32 KB (gemm branch only)
    int b = blockIdx.x;
    int g = b / 9;
    int r = b - g * 9;
    int tid = threadIdx.x;

    if (r == 2 || r == 6 || r == 8) {
        // ---- hist branch
        int hb = g * 3 + (r == 6 ? 1 : (r == 8 ? 2 : 0));
        if (hb >= H) return;
        int e = hb * 256 + tid;
        if (e < E) rank[e] = atomicAdd(&counts[src_id[e]], 1);
        return;
    }
    if (r != 0 && r != 4) {
        // ---- gemv branch: 8 lanes/row, 8 x float4/lane, 32 rows/block
        int vb = g * 4 + (r == 3 ? 1 : (r == 5 ? 2 : (r == 7 ? 3 : 0)));
        if (vb >= V) return;
        int row = vb * 32 + (tid >> 3);
        if (row >= Ms) return;
        int k = tid & 7;
        const float4* R = (const float4*)(X + (size_t)row * IN_DIM);
        const float4* W4 = (const float4*)w;
        float s = 0.f;
        #pragma unroll
        for (int c = 0; c < 8; ++c) {
            float4 x = R[k + 8 * c];
            float4 wv = W4[k + 8 * c];
            s += x.x * wv.x + x.y * wv.y + x.z * wv.z + x.w * wv.w;
        }
        s += __shfl_xor(s, 1);
        s += __shfl_xor(s, 2);
        s += __shfl_xor(s, 4);
        if (k == 0) score_i[row] = s;
        return;
    }
    // ---- gemm branch (block-uniform; __syncthreads is safe)
    int gb = g * 2 + (r == 4 ? 1 : 0);
    if (gb >= G) return;
    int w4 = tid >> 6;
    int l = tid & 63;
    int bm = gb * 64;

    int srow = tid >> 4;          // 0..15
    int kcol = (tid & 15) * 4;    // 0..60

    float aw[8];
    #pragma unroll
    for (int j = 0; j < 8; ++j) aw[j] = a_hi[j * 16 + (l & 15)];

    f32x4 acc[8];
    f32x4 zero = {0.f, 0.f, 0.f, 0.f};
    #pragma unroll
    for (int j = 0; j < 8; ++j) acc[j] = zero;

    float4 pre[16];
    #pragma unroll
    for (int p = 0; p < 4; ++p) {
        int grow = bm + srow + p * 16;
        const float* rp = A + (size_t)(grow < Mt ? grow : Mt - 1) * IN_DIM;
        bool ok = grow < Mt;
        #pragma unroll
        for (int c = 0; c < 4; ++c) {
            float4 v = *(const float4*)(rp + c * 64 + kcol);
            pre[p * 4 + c] = ok ? v : make_float4(0.f, 0.f, 0.f, 0.f);
        }
    }
    #pragma unroll
    for (int p = 0; p < 4; ++p) {
        int row = srow + p * 16;
        #pragma unroll
        for (int c = 0; c < 4; ++c) {
            float4 v = pre[p * 4 + c];
            unsigned int b0 = (unsigned int)f2bf(v.x) | ((unsigned int)f2bf(v.y) << 16);
            unsigned int b1 = (unsigned int)f2bf(v.z) | ((unsigned int)f2bf(v.w) << 16);
            unsigned int byteoff =
                (unsigned int)(row * 512 + (c * 64 + kcol) * 2) ^ ((row & 7) << 4);
            *(uint2*)((char*)As + byteoff) = make_uint2(b0, b1);
        }
    }
    __syncthreads();

    __builtin_amdgcn_s_setprio(1);   // T5: favor MFMA waves vs co-resident mem waves
    #pragma unroll
    for (int kc = 0; kc < 8; ++kc) {
        int row = w4 * 16 + (l & 15);
        unsigned int byteoff =
            (unsigned int)(row * 512 + kc * 64 + (l >> 4) * 16) ^ ((row & 7) << 4);
        bf16x8 af = *(const bf16x8*)((const char*)As + byteoff);
        #pragma unroll
        for (int j = 0; j < 8; ++j) {
            bf16x8 bfj = *(const bf16x8*)(Wswz + ((size_t)(kc * 8 + j) * 64 + l) * 8);
            acc[j] = __builtin_amdgcn_mfma_f32_16x16x32_bf16(af, bfj, acc[j], 0, 0, 0);
        }
    }
    __builtin_amdgcn_s_setprio(0);

    #pragma unroll
    for (int rr = 0; rr < 4; ++rr) {
        int row = bm + w4 * 16 + (l >> 4) * 4 + rr;
        if (row < Mt) {
            float s = 0.f;
            #pragma unroll
            for (int j = 0; j < 8; ++j) {
                float v = acc[j][rr];
                Hb[(size_t)row * OUT_DIM + j * 16 + (l & 15)] = f2bf(v);
                s += v * aw[j];
            }
            s += __shfl_xor(s, 1); s += __shfl_xor(s, 2);
            s += __shfl_xor(s, 4); s += __shfl_xor(s, 8);
            if ((l & 15) == 0) score_j[row] = s;
        }
    }
}

// ---------------- 2-level exclusive scan (partial offs + block offsets)
__global__ __launch_bounds__(256) void scan1_kernel(
    const int* __restrict__ counts, int* __restrict__ offs,
    int* __restrict__ blockSums, int n) {
    __shared__ int sd[256];
    int b = blockIdx.x, tid = threadIdx.x;
    int base = b * 1024 + tid * 4;
    int v0 = base + 0 < n ? counts[base + 0] : 0;
    int v1 = base + 1 < n ? counts[base + 1] : 0;
    int v2 = base + 2 < n ? counts[base + 2] : 0;
    int v3 = base + 3 < n ? counts[base + 3] : 0;
    int p1 = v0, p2 = v0 + v1, p3 = v0 + v1 + v2;
    int tsum = p3 + v3;
    sd[tid] = tsum;
    __syncthreads();
    #pragma unroll
    for (int off = 1; off < 256; off <<= 1) {
        int t = tid >= off ? sd[tid - off] : 0;
        __syncthreads();
        sd[tid] += t;
        __syncthreads();
    }
    int ex = sd[tid] - tsum;
    if (base + 0 < n) offs[base + 0] = ex;
    if (base + 1 < n) offs[base + 1] = ex + p1;
    if (base + 2 < n) offs[base + 2] = ex + p2;
    if (base + 3 < n) offs[base + 3] = ex + p3;
    if (tid == 255) blockSums[b] = sd[255];
}

__global__ __launch_bounds__(256) void scan2_kernel(
    const int* __restrict__ blockSums, int* __restrict__ blockOffs, int nb) {
    __shared__ int sd[256];
    int tid = threadIdx.x;
    int v = tid < nb ? blockSums[tid] : 0;
    sd[tid] = v;
    __syncthreads();
    #pragma unroll
    for (int off = 1; off < 256; off <<= 1) {
        int t = tid >= off ? sd[tid - off] : 0;
        __syncthreads();
        sd[tid] += t;
        __syncthreads();
    }
    blockOffs[tid] = sd[tid] - v;
}

// ---------------- fused scatter, zero atomics; blockOffs folded in
__global__ __launch_bounds__(256) void scatter_fused_kernel(
    const int* __restrict__ src_id, const int* __restrict__ tgt_id,
    const float* __restrict__ score_i, const float* __restrict__ score_j,
    const int* __restrict__ offs, const int* __restrict__ blockOffs,
    const int* __restrict__ rank, uint2* __restrict__ pairs, int E) {
    int e = blockIdx.x * blockDim.x + threadIdx.x;
    if (e >= E) return;
    int s = src_id[e], t = tgt_id[e];
    float x = score_i[s] + score_j[t];
    x = x > 0.f ? x : LEAKY * x;
    x = fminf(30.f, fmaxf(-30.f, x));
    float ex = expf(x);
    int p = offs[s] + blockOffs[s >> 10] + rank[e];
    pairs[p] = make_uint2((unsigned int)t, __float_as_uint(ex));
}

// ---------------- aggregate: wave per node, 4 edges in flight, inline denom, fused ELU
__global__ __launch_bounds__(256) void agg_kernel(
    const uint2* __restrict__ pairs, const int* __restrict__ offs,
    const int* __restrict__ blockOffs, const unsigned short* __restrict__ hjb,
    float* __restrict__ out, int N, int E) {
    int node = (int)((blockIdx.x * (long long)blockDim.x + threadIdx.x) >> 6);
    if (node >= N) return;
    int lane = threadIdx.x & 63;
    int q  = lane >> 4;
    int cl = lane & 15;
    int beg = offs[node] + blockOffs[node >> 10];
    int end = (node + 1 < N) ? offs[node + 1] + blockOffs[(node + 1) >> 10] : E;
    int deg = end - beg;
    float den = 0.f;
    float acc[8];
    #pragma unroll
    for (int i = 0; i < 8; ++i) acc[i] = 0.f;

    int iters = (deg + 3) >> 2;
    for (int it = 0; it < iters; ++it) {
        int e = q + 4 * it;
        bool valid = e < deg;
        int idx = beg + (valid ? e : 0);
        uint2 tw = pairs[idx];
        int t = (int)tw.x;
        float wgt = valid ? __uint_as_float(tw.y) : 0.f;
        den += wgt;
        uint4 u = *(const uint4*)(hjb + (size_t)t * OUT_DIM + cl * 8);
        acc[0] += bf2f(u.x & 0xffffu) * wgt;
        acc[1] += bf2f(u.x >> 16) * wgt;
        acc[2] += bf2f(u.y & 0xffffu) * wgt;
        acc[3] += bf2f(u.y >> 16) * wgt;
        acc[4] += bf2f(u.z & 0xffffu) * wgt;
        acc[5] += bf2f(u.z >> 16) * wgt;
        acc[6] += bf2f(u.w & 0xffffu) * wgt;
        acc[7] += bf2f(u.w >> 16) * wgt;
    }
    den += __shfl_xor(den, 16);
    den += __shfl_xor(den, 32);
    float inv = 1.f / (den + 1e-8f);
    #pragma unroll
    for (int i = 0; i < 8; ++i) {
        acc[i] += __shfl_xor(acc[i], 16);
        acc[i] += __shfl_xor(acc[i], 32);
        acc[i] *= inv;
        acc[i] = acc[i] > 0.f ? acc[i] : expm1f(acc[i]);
    }
    if (lane < 16) {
        float4 v0 = make_float4(acc[0], acc[1], acc[2], acc[3]);
        float4 v1 = make_float4(acc[4], acc[5], acc[6], acc[7]);
        *(float4*)(out + (size_t)node * OUT_DIM + cl * 8) = v0;
        *(float4*)(out + (size_t)node * OUT_DIM + cl * 8 + 4) = v1;
    }
}

// ---------------- fallback path (atomic scatter) if ws too small
__global__ __launch_bounds__(256) void edge_pass1_kernel(
    const int* __restrict__ src_id, const int* __restrict__ tgt_id,
    const float* __restrict__ score_i, const float* __restrict__ score_j,
    float* __restrict__ exp_e, float* __restrict__ denom, int E) {
    int e = blockIdx.x * blockDim.x + threadIdx.x;
    if (e >= E) return;
    int s = src_id[e], t = tgt_id[e];
    float x = score_i[s] + score_j[t];
    x = x > 0.f ? x : LEAKY * x;
    x = fminf(30.f, fmaxf(-30.f, x));
    float ex = expf(x);
    exp_e[e] = ex;
    atomicAdd(&denom[s], ex);
}

__global__ __launch_bounds__(256) void edge_pass2_kernel(
    const int* __restrict__ src_id, const int* __restrict__ tgt_id,
    const unsigned short* __restrict__ hjb, const float* __restrict__ exp_e,
    const float* __restrict__ denom, float* __restrict__ out, int E) {
    int idx = blockIdx.x * blockDim.x + threadIdx.x;
    int e = idx >> 6;
    if (e >= E) return;
    int lane = idx & 63;
    int s = src_id[e], t = tgt_id[e];
    float alpha = exp_e[e] / (denom[s] + 1e-8f);
    unsigned int u = *(const unsigned int*)(hjb + (size_t)t * OUT_DIM + lane * 2);
    atomicAdd(out + (size_t)s * OUT_DIM + lane * 2 + 0, bf2f(u & 0xffffu) * alpha);
    atomicAdd(out + (size_t)s * OUT_DIM + lane * 2 + 1, bf2f(u >> 16) * alpha);
}

__global__ __launch_bounds__(256) void elu_kernel(float* __restrict__ out, int n4) {
    int i = blockIdx.x * blockDim.x + threadIdx.x;
    if (i >= n4) return;
    float4 v = ((float4*)out)[i];
    v.x = v.x > 0.f ? v.x : expm1f(v.x);
    v.y = v.y > 0.f ? v.y : expm1f(v.y);
    v.z = v.z > 0.f ? v.z : expm1f(v.z);
    v.w = v.w > 0.f ? v.w : expm1f(v.w);
    ((float4*)out)[i] = v;
}

extern "C" void kernel_launch(void* const* d_in, const int* in_sizes, int n_in,
                              void* d_out, int out_size, void* d_ws, size_t ws_size,
                              hipStream_t stream) {
    const float* src   = (const float*)d_in[0];
    const float* tgt   = (const float*)d_in[1];
    const float* W_src = (const float*)d_in[2];
    const float* W_tgt = (const float*)d_in[3];
    const float* a     = (const float*)d_in[4];
    const int*   edge  = (const int*)d_in[5];

    int N_src = in_sizes[0] / IN_DIM;
    int N_tgt = in_sizes[1] / IN_DIM;
    int E     = in_sizes[5] / 2;
    const int* src_id = edge;
    const int* tgt_id = edge + E;

    float* out = (float*)d_out;

    char* ws = (char*)d_ws;
    size_t off = 0;
    auto alloc = [&](size_t bytes) {
        void* p = ws + off;
        off += (bytes + 255) & ~(size_t)255;
        return p;
    };

    unsigned short* hjb  = (unsigned short*)alloc((size_t)N_tgt * OUT_DIM * 2);
    float* score_i = (float*)alloc((size_t)N_src * 4);
    float* score_j = (float*)alloc((size_t)N_tgt * 4);
    float* wcomb   = (float*)alloc(256 * 4);
    unsigned short* Wswz = (unsigned short*)alloc(4096 * 8 * 2);
    int*   counts    = (int*)alloc(((size_t)N_src + 3) / 4 * 16);  // int4-aligned
    int*   offs      = (int*)alloc((size_t)(N_src + 1) * 4);
    int*   blockSums = (int*)alloc(256 * 4);
    int*   blockOffs = (int*)alloc(256 * 4);
    float* denom     = (float*)alloc((size_t)N_src * 4);   // fallback only
    float* exp_e     = (float*)alloc((size_t)E * 4);       // fallback only
    size_t fb_need = off;
    int*   rank      = (int*)alloc((size_t)E * 4);
    uint2* pairs     = (uint2*)alloc((size_t)E * 8);
    size_t csr_need = off;
    (void)fb_need;

    bool use_csr = (ws_size >= csr_need);

    int n4 = (N_src + 3) / 4;                 // count of int4s to zero
    int zblocks = (n4 + 255) / 256;
    prep_kernel<<<17 + zblocks, 256, 0, stream>>>(
        W_src, W_tgt, a, wcomb, Wswz, (int4*)counts, n4);

    // fused phase 1: gemm + gemv + hist (pattern of 9: 2 gemm, 4 gemv, 3 hist)
    int G = (N_tgt + 63) / 64;
    int V = (N_src + 31) / 32;
    int H = (E + 255) / 256;
    int gmax = (G + 1) / 2;
    int vmax = (V + 3) / 4;
    int hmax = (H + 2) / 3;
    int groups = gmax > vmax ? gmax : vmax;
    if (hmax > groups) groups = hmax;
    phase1_kernel<<<groups * 9, 256, 0, stream>>>(
        tgt, Wswz, a + OUT_DIM, hjb, score_j, N_tgt, G,
        src, wcomb, score_i, N_src, V,
        src_id, counts, rank, E, H);

    if (use_csr) {
        int nb = (N_src + 1023) / 1024;
        scan1_kernel<<<nb, 256, 0, stream>>>(counts, offs, blockSums, N_src);
        scan2_kernel<<<1, 256, 0, stream>>>(blockSums, blockOffs, nb);
        scatter_fused_kernel<<<(E + 255) / 256, 256, 0, stream>>>(
            src_id, tgt_id, score_i, score_j, offs, blockOffs, rank, pairs, E);
        agg_kernel<<<(N_src + 3) / 4, 256, 0, stream>>>(
            pairs, offs, blockOffs, hjb, out, N_src, E);
    } else {
        hipMemsetAsync(out, 0, (size_t)N_src * OUT_DIM * sizeof(float), stream);
        hipMemsetAsync(denom, 0, (size_t)N_src * sizeof(float), stream);
        edge_pass1_kernel<<<(E + 255) / 256, 256, 0, stream>>>(
            src_id, tgt_id, score_i, score_j, exp_e, denom, E);
        edge_pass2_kernel<<<(int)(((long long)E * 64 + 255) / 256), 256, 0, stream>>>(
            src_id, tgt_id, hjb, exp_e, denom, out, E);
        elu_kernel<<<(N_src * OUT_DIM / 4 + 255) / 256, 256, 0, stream>>>(
            out, N_src * OUT_DIM / 4);
    }
}